// Round 16
// baseline (237.557 us; speedup 1.0000x reference)
//
#include <hip/hip_runtime.h>
#include <hip/hip_bf16.h>
#include <type_traits>

// SelfAttention fused block, MI355X/gfx950.
// R25: resubmit of R24 (bench infra failed: "container failed twice", no
//      kernel verdict — experiment carries zero information; kernel
//      re-audited for hang/fault paths: LDS regions fit exactly, global
//      addresses in-range, no divergent barriers, per-wave counters only).
//      k-split flash: waves split the K-RANGE instead of the q-range:
//      QBLK=64 (1024 blocks, XCD-affine), each wave owns a PRIVATE 16KB
//      K/V buffer and independently streams tiles kt=j*4+w (stage 16
//      gl_lds/lane -> vmcnt(0) -> compute all 64 q-rows -> lgkmcnt(0)).
//      Zero barriers in the main loop; each K/V tile read from LDS ONCE
//      per block (4x less read amplification than the lockstep scheme —
//      R18 showed traffic cancels TLP when both scale). Epilogue: two
//      __syncthreads, partial-O + sums through dead LDS, wave w stores
//      q-rows 16w..16w+15. Everything else byte-identical to R23
//      (best 208.9us). 5 launches.

typedef __hip_bfloat16 bf16;
typedef __attribute__((ext_vector_type(8))) short bf16x8;
typedef __attribute__((ext_vector_type(4))) float f32x4;

#define MFMA_BF16(a, b, c) __builtin_amdgcn_mfma_f32_16x16x32_bf16((a), (b), (c), 0, 0, 0)

__device__ __forceinline__ float us2f(unsigned short u) {
  unsigned int v = ((unsigned int)u) << 16;
  return __builtin_bit_cast(float, v);
}

__device__ __forceinline__ unsigned pack_bf16x2(float a, float b) {  // RNE (epilogues)
  union { __hip_bfloat162 h; unsigned u; } cv;
  cv.h = __float22bfloat162_rn(float2{a, b});
  return cv.u;
}

__device__ __forceinline__ unsigned pack_bf16x2_trunc(float a, float b) {  // 1x v_perm
  return __builtin_amdgcn_perm(__builtin_bit_cast(unsigned, b),
                               __builtin_bit_cast(unsigned, a), 0x07060302u);
}

// async global->LDS, 16B per lane; lane i's dest = wave-uniform base + i*16
__device__ __forceinline__ void gl_lds16(const bf16* g, bf16* l) {
  __builtin_amdgcn_global_load_lds(
      (const __attribute__((address_space(1))) void*)g,
      (__attribute__((address_space(3))) void*)l, 16, 0, 0);
}

// raw barrier + compile-time scheduling fence: nothing (esp. plain LDS
// loads) may move across this sync point in either direction.
__device__ __forceinline__ void barrier_pinned() {
  __builtin_amdgcn_s_barrier();
  __builtin_amdgcn_sched_barrier(0);
}

// m204 bijective XCD swizzle; requires nwg % 8 == 0.
__device__ __forceinline__ int xcd_swz(int orig, int nwg) {
  return (orig & 7) * (nwg >> 3) + (orig >> 3);
}

// ---------------- wave-per-row LayerNorm core (D=1024, no LDS/barriers) ----------------
template <typename TIN>
__device__ __forceinline__ void ln_wave(
    const TIN* __restrict__ in, const float* __restrict__ gamma,
    const float* __restrict__ beta, bf16* __restrict__ out,
    int stride, float sc, int row)
{
  const int lane = threadIdx.x & 63;
  const TIN* rp = in + (size_t)row * stride;
  float x[16];
#pragma unroll
  for (int j = 0; j < 4; ++j) {
    if constexpr (std::is_same_v<TIN, float>) {
      float4 u = *(const float4*)(rp + j * 256 + lane * 4);
      x[j * 4 + 0] = u.x; x[j * 4 + 1] = u.y;
      x[j * 4 + 2] = u.z; x[j * 4 + 3] = u.w;
    } else {
      ushort4 u = *(const ushort4*)(rp + j * 256 + lane * 4);
      x[j * 4 + 0] = us2f(u.x); x[j * 4 + 1] = us2f(u.y);
      x[j * 4 + 2] = us2f(u.z); x[j * 4 + 3] = us2f(u.w);
    }
  }
  float s = 0.0f, s2 = 0.0f;
#pragma unroll
  for (int i = 0; i < 16; ++i) { s += x[i]; s2 += x[i] * x[i]; }
#pragma unroll
  for (int m = 1; m < 64; m <<= 1) {
    s += __shfl_xor(s, m);
    s2 += __shfl_xor(s2, m);
  }
  const float mu = s * (1.0f / 1024.0f);
  const float rs = rsqrtf(s2 * (1.0f / 1024.0f) - mu * mu + 1e-5f);
  bf16* op = out + (size_t)row * 1024;
#pragma unroll
  for (int j = 0; j < 4; ++j) {
    float4 g4 = *(const float4*)(gamma + j * 256 + lane * 4);
    float4 b4 = *(const float4*)(beta + j * 256 + lane * 4);
    uint2 o;
    o.x = pack_bf16x2(((x[j * 4 + 0] - mu) * rs * g4.x + b4.x) * sc,
                      ((x[j * 4 + 1] - mu) * rs * g4.y + b4.y) * sc);
    o.y = pack_bf16x2(((x[j * 4 + 2] - mu) * rs * g4.z + b4.z) * sc,
                      ((x[j * 4 + 3] - mu) * rs * g4.w + b4.w) * sc);
    *(uint2*)(op + j * 256 + lane * 4) = o;
  }
}

// ---------------- standalone LN pair (P3): 4 rows/block, wave-per-row ----------------
template <typename TIN>
__global__ __launch_bounds__(256) void ln2_kernel(
    const TIN* __restrict__ in0, const TIN* __restrict__ in1, int stride,
    const float* __restrict__ g0, const float* __restrict__ b0,
    const float* __restrict__ g1, const float* __restrict__ b1,
    bf16* __restrict__ out0, bf16* __restrict__ out1,
    float sc0, float sc1)
{
  const int w = threadIdx.x >> 6;
  const int lnid = blockIdx.x * 4 + w;
  const int row = lnid >> 1, which = lnid & 1;
  ln_wave<TIN>(which ? in1 : in0, which ? g1 : g0, which ? b1 : b0,
               which ? out1 : out0, stride, which ? sc1 : sc0, row);
}

// ---------------- 64x64 f32->bf16 transpose tile core ----------------
__device__ __forceinline__ void transpose_core(
    const float* __restrict__ in, bf16* __restrict__ out, int C,
    int r0, int c0, float (*tile)[68])
{
  const int R = 1024;
  const int t = threadIdx.x;
  const int lr = t >> 2, lc = (t & 3) * 16;
  const float* src = in + (size_t)(r0 + lr) * C + (c0 + lc);
#pragma unroll
  for (int i = 0; i < 4; ++i) {
    float4 u = *(const float4*)(src + i * 4);
    tile[lr][lc + i * 4 + 0] = u.x;
    tile[lr][lc + i * 4 + 1] = u.y;
    tile[lr][lc + i * 4 + 2] = u.z;
    tile[lr][lc + i * 4 + 3] = u.w;
  }
  __syncthreads();
  __align__(16) bf16 tmp[16];
#pragma unroll
  for (int j = 0; j < 16; ++j) tmp[j] = __float2bfloat16(tile[lc + j][lr]);
  bf16* dst = out + (size_t)(c0 + lr) * R + (r0 + lc);
  *(bf16x8*)dst       = *(const bf16x8*)&tmp[0];
  *(bf16x8*)(dst + 8) = *(const bf16x8*)&tmp[8];
}

// ---------------- prep: input LNs (2048 blocks, wave-per-row) + 3 weight transposes (1024) ----------------
__global__ __launch_bounds__(256) void prep_kernel(
    const float* __restrict__ keys, const float* __restrict__ values,
    const float* __restrict__ qk_g, const float* __restrict__ qk_b,
    const float* __restrict__ val_g, const float* __restrict__ val_b,
    bf16* __restrict__ keys_ln, bf16* __restrict__ values_ln,
    const float* __restrict__ w_qk, bf16* __restrict__ wqkT,
    const float* __restrict__ w_v, bf16* __restrict__ wvT,
    const float* __restrict__ w_out, bf16* __restrict__ woutT)
{
  __shared__ float tile[64][68];
  const int bid = blockIdx.x;
  if (bid < 2048) {
    const int w = threadIdx.x >> 6;
    const int lnid = bid * 4 + w;            // [0, 8192)
    const int row = lnid >> 1, which = lnid & 1;
    ln_wave<float>(which ? values : keys, which ? val_g : qk_g,
                   which ? val_b : qk_b, which ? values_ln : keys_ln,
                   1024, 1.0f, row);
  } else {
    const int tz = bid - 2048;
    if (tz < 512) {
      transpose_core(w_qk, wqkT, 2048, (tz >> 5) * 64, (tz & 31) * 64, tile);
    } else if (tz < 768) {
      const int s = tz - 512;
      transpose_core(w_v, wvT, 1024, (s >> 4) * 64, (s & 15) * 64, tile);
    } else {
      const int s = tz - 768;
      transpose_core(w_out, woutT, 1024, (s >> 4) * 64, (s & 15) * 64, tile);
    }
  }
}

// ---------------- GEMM core: C(M,N) = A(M,K) @ Bt(N,K)^T (+bias), bf16 in, fp32 accum ----------------
template <int BM, int BN, int TMODE, typename TOUT>
__device__ __forceinline__ void gemm_core(
    const bf16* __restrict__ A, const bf16* __restrict__ Bt,
    const float* __restrict__ bias, TOUT* __restrict__ C,
    int N, int K, int has_bias, int bx, int by, bf16* smem)
{
  constexpr int MT = BM / 32, NT = BN / 32;     // 16x16 frags per wave
  constexpr int ASL = BM / 32, BSL = BN / 32;   // 16B staging slots per thread (BK=64)
  constexpr int BUFE = (BM + BN) * 64;          // elements per buffer
  const int t = threadIdx.x;
  const int w = t >> 6, lane = t & 63, l15 = lane & 15, quad = lane >> 4;
  const int wy = w >> 1, wx = w & 1;
  const bf16* Ab = A + (size_t)by * BM * K;
  const bf16* Bb = Bt + (size_t)bx * BN * K;
  f32x4 acc[MT][NT] = {};

  const bf16* aptr[ASL];
  const bf16* bptr[BSL];
#pragma unroll
  for (int i = 0; i < ASL; ++i) {
    int s = i * 256 + t, row = s >> 3, c = (s & 7) ^ (row & 7);
    aptr[i] = Ab + (size_t)row * K + (c << 3);
  }
#pragma unroll
  for (int i = 0; i < BSL; ++i) {
    int s = i * 256 + t, row = s >> 3, c = (s & 7) ^ (row & 7);
    bptr[i] = Bb + (size_t)row * K + (c << 3);
  }

  auto stage = [&](bf16* buf, int kc) {
#pragma unroll
    for (int i = 0; i < ASL; ++i)
      gl_lds16(aptr[i] + kc, buf + (i * 256 + t) * 8);
#pragma unroll
    for (int i = 0; i < BSL; ++i)
      gl_lds16(bptr[i] + kc, buf + BM * 64 + (i * 256 + t) * 8);
  };

  const int sw = (quad ^ (l15 & 7)) << 3;
  const int NK = K >> 6;

  stage(smem, 0);  // prologue: tile 0 into buf 0

  for (int kt = 0; kt < NK; ++kt) {
    const int cur = kt & 1;
    bf16* lA = smem + cur * BUFE;
    bf16* lB = lA + BM * 64;
    barrier_pinned();  // all waves done reading buf cur^1
    if (kt + 1 < NK) {
      stage(smem + (cur ^ 1) * BUFE, (kt + 1) << 6);
      if constexpr (ASL + BSL == 8)
        asm volatile("s_waitcnt vmcnt(8)" ::: "memory");  // tile kt landed; kt+1 in flight
      else if constexpr (ASL + BSL == 6)
        asm volatile("s_waitcnt vmcnt(6)" ::: "memory");
      else
        asm volatile("s_waitcnt vmcnt(4)" ::: "memory");
    } else {
      asm volatile("s_waitcnt vmcnt(0)" ::: "memory");
    }
    barrier_pinned();  // staged data visible to all waves; reads pinned below

#pragma unroll
    for (int h = 0; h < 2; ++h) {
      const int so = sw ^ (h << 5);
      bf16x8 af[MT], bfr[NT];
#pragma unroll
      for (int mt = 0; mt < MT; ++mt)
        af[mt] = *(const bf16x8*)&lA[(wy * (BM / 2) + mt * 16 + l15) * 64 + so];
#pragma unroll
      for (int nt = 0; nt < NT; ++nt)
        bfr[nt] = *(const bf16x8*)&lB[(wx * (BN / 2) + nt * 16 + l15) * 64 + so];
#pragma unroll
      for (int mt = 0; mt < MT; ++mt)
#pragma unroll
        for (int nt = 0; nt < NT; ++nt)
          acc[mt][nt] = MFMA_BF16(af[mt], bfr[nt], acc[mt][nt]);
    }
  }

  if constexpr (TMODE == 1) {
    constexpr int STR = BM + 8;   // keeps d*STR*2 bytes 16B-aligned
    static_assert(BN * STR <= 2 * BUFE, "lOut must fit staging buffers");
    bf16* lOut = smem;            // aliases dead staging buffers
    __syncthreads();
#pragma unroll
    for (int mt = 0; mt < MT; ++mt)
#pragma unroll
      for (int nt = 0; nt < NT; ++nt) {
        const int d = wx * (BN / 2) + nt * 16 + l15;
        const int n = wy * (BM / 2) + mt * 16 + quad * 4;
        uint2 pk;
        pk.x = pack_bf16x2(acc[mt][nt][0], acc[mt][nt][1]);
        pk.y = pack_bf16x2(acc[mt][nt][2], acc[mt][nt][3]);
        *(uint2*)&lOut[d * STR + n] = pk;
      }
    __syncthreads();
    const int row0 = by * BM;
    const int bidx = row0 >> 11, n0 = row0 & 2047;
    const int col0 = bx * BN;
    constexpr int CPR = BM / 32;                  // 32-el chunks per d-row
    constexpr int NITER = (BN * CPR) / 256;
#pragma unroll
    for (int it = 0; it < NITER; ++it) {
      const int idx = it * 256 + t;
      const int d = idx / CPR, off = (idx % CPR) * 32;
      const bf16* srcp = &lOut[d * STR + off];
      bf16* g = (bf16*)C + ((size_t)(bidx << 10) + col0 + d) * 2048 + n0 + off;
#pragma unroll
      for (int j = 0; j < 4; ++j)
        *(bf16x8*)(g + j * 8) = *(const bf16x8*)(srcp + j * 8);
    }
  } else {
    const int row_base = by * BM + wy * (BM / 2);
    const int col_base = bx * BN + wx * (BN / 2);
#pragma unroll
    for (int mt = 0; mt < MT; ++mt)
#pragma unroll
      for (int nt = 0; nt < NT; ++nt) {
        const int col = col_base + nt * 16 + l15;
        const float bb = has_bias ? bias[col] : 0.0f;
#pragma unroll
        for (int r = 0; r < 4; ++r) {
          const int row = row_base + mt * 16 + quad * 4 + r;
          float v = acc[mt][nt][r] + bb;
          if constexpr (std::is_same_v<TOUT, bf16>)
            C[(size_t)row * N + col] = __float2bfloat16(v);
          else
            C[(size_t)row * N + col] = v;
        }
      }
  }
}

// single-GEMM wrapper (P5) with flattened XCD swizzle (nwg % 8 == 0)
template <int BM, int BN, int TMODE, typename TOUT>
__global__ __launch_bounds__(256) void gemm_bt_kernel(
    const bf16* __restrict__ A, const bf16* __restrict__ Bt,
    const float* __restrict__ bias, TOUT* __restrict__ C,
    int N, int K, int has_bias)
{
  __shared__ __align__(16) bf16 smem[2 * (BM + BN) * 64];
  const int nwg = gridDim.x * gridDim.y;
  const int orig = blockIdx.y * gridDim.x + blockIdx.x;
  const int s = xcd_swz(orig, nwg);
  gemm_core<BM, BN, TMODE, TOUT>(A, Bt, bias, C, N, K, has_bias,
                                 s % gridDim.x, s / gridDim.x, smem);
}

// dual GEMM (P2): qk = keys_ln @ wqkT (512 blocks, 128x128) +
//                 vt = values_ln @ wvT (256 blocks, 128x128, TMODE1)
__global__ __launch_bounds__(256) void gemm_dual_kernel(
    const bf16* __restrict__ A0, const bf16* __restrict__ B0, bf16* __restrict__ C0,
    const bf16* __restrict__ A1, const bf16* __restrict__ B1, bf16* __restrict__ C1)
{
  __shared__ __align__(16) bf16 smem[2 * 256 * 64];  // 64KB -> 2 blocks/CU
  const int bid = blockIdx.x;
  if (bid < 512) {
    const int s = xcd_swz(bid, 512);
    gemm_core<128, 128, 0, bf16>(A0, B0, nullptr, C0, 2048, 1024, 0,
                                 s & 15, s >> 4, smem);
  } else {
    const int s = xcd_swz(bid - 512, 256);
    gemm_core<128, 128, 1, bf16>(A1, B1, nullptr, C1, 1024, 1024, 0,
                                 s & 7, s >> 3, smem);
  }
}

// ---------------- Flash attention (R24/R25): k-split waves, wave-private K/V, no loop barriers ----------------
// QBLK=64 (4 msets of 16 q-rows, all computed by every wave). Wave w
// processes K/V tiles kt = j*4+w (j=0..7) through its PRIVATE 16KB buffer:
// stage -> vmcnt(0) -> compute -> lgkmcnt(0) -> next. K rows permuted at
// staging by g(row) within each 64-granule so the QK^T C/D fragment,
// exp'd and packed, IS the 16x16x32 PV B-operand (verified R11-R23).
// Epilogue: __syncthreads; partial O (64KB, dead K/V region) + quad-
// reduced sums (dead Q region) to LDS; __syncthreads; wave w combines
// 4 partials for mset w and stores q-rows 16w..16w+15.
__global__ __launch_bounds__(256) void flash_kernel(
    const bf16* __restrict__ Q, const bf16* __restrict__ Km,
    const bf16* __restrict__ Vt, bf16* __restrict__ O)
{
  __shared__ __align__(16) bf16 smem[4096 + 4 * 8192];  // 8KB Q + 4x16KB wave K/V = 72KB
  bf16* lQ = smem;                          // 64x64
  const int t = threadIdx.x;
  const int w = t >> 6, lane = t & 63, l15 = lane & 15, quad = lane >> 4;
  bf16* kbuf = smem + 4096 + w * 8192;      // wave-private 64x64 K
  bf16* vbuf = kbuf + 4096;                 // wave-private 64x64 V
  const int bid = blockIdx.x;
  const int qt = (bid >> 3) & 31;               // q-tile (64 rows) within (b,h)
  const int bh = (bid & 7) + ((bid >> 8) << 3); // XCD-affine (b,h) group
  const int b = bh >> 4, h = bh & 15;
  const int qrow0 = b * 2048 + qt * 64;
  const bf16* qbase = Q + (size_t)qrow0 * 1024 + h * 64;
  const bf16* kbase = Km + ((size_t)(b * 2048)) * 1024 + h * 64;
  const bf16* vbase = Vt + ((size_t)(b * 1024 + h * 64)) * 2048;

  // prologue: cooperative Q staging (256 threads, 2 slots each) — R18-verified
#pragma unroll
  for (int i = 0; i < 2; ++i) {
    int s = i * 256 + t;
    int row = s >> 3, c = (s & 7) ^ (row & 7);
    gl_lds16(qbase + (size_t)row * 1024 + (c << 3), lQ + s * 8);
  }
  asm volatile("s_waitcnt vmcnt(0)" ::: "memory");
  barrier_pinned();

  const int sw = (quad ^ (l15 & 7)) << 3;
  bf16x8 qf[4][2];
#pragma unroll
  for (int m = 0; m < 4; ++m) {
    const int row = m * 16 + l15;
    qf[m][0] = *(const bf16x8*)&lQ[row * 64 + sw];
    qf[m][1] = *(const bf16x8*)&lQ[row * 64 + (sw ^ 32)];
  }

  // per-lane staging constants: slot s = i*64+lane -> row = i*8 + (lane>>3),
  // row&7 == lane>>3, so chunk offset c = (lane&7)^(lane>>3) is lane-constant.
  const int hh = lane >> 3;
  const int cK = ((lane & 7) ^ hh) << 3;     // element offset of this lane's chunk
  int gr[8];                                 // permuted K row per i (lane-constant)
#pragma unroll
  for (int i = 0; i < 8; ++i) {
    int row = (i << 3) | hh;
    gr[i] = (row & 0x23) | ((row & 0x0C) << 1) | ((row & 0x10) >> 2);
  }

  f32x4 o_acc[4][4] = {};  // [dt][mset]: O^T row d = dt*16+quad*4+r, col m = mset*16+l15
  float l_sum[4] = {};     // per-lane partial row sums (this wave's k-range)

  for (int j = 0; j < 8; ++j) {
    const int kt = j * 4 + w;     // wave-private tile index, covers 0..31
    const int kro = kt << 6;      // 64 k-rows (or 64 v-cols) per tile
    // stage K (permuted rows) + V into wave-private buffers
#pragma unroll
    for (int i = 0; i < 8; ++i) {
      gl_lds16(kbase + (size_t)(kro + gr[i]) * 1024 + cK, kbuf + i * 512 + lane * 8);
      gl_lds16(vbase + (size_t)((i << 3) | hh) * 2048 + kro + cK, vbuf + i * 512 + lane * 8);
    }
    asm volatile("s_waitcnt vmcnt(0)" ::: "memory");  // own loads only (per-wave counter)
    __builtin_amdgcn_sched_barrier(0);

    bf16x8 kf[4][2];
#pragma unroll
    for (int nt = 0; nt < 4; ++nt) {
      kf[nt][0] = *(const bf16x8*)&kbuf[(nt * 16 + l15) * 64 + sw];
      kf[nt][1] = *(const bf16x8*)&kbuf[(nt * 16 + l15) * 64 + (sw ^ 32)];
    }
    bf16x8 vf[4][2];
#pragma unroll
    for (int dt = 0; dt < 4; ++dt) {
      vf[dt][0] = *(const bf16x8*)&vbuf[(dt * 16 + l15) * 64 + sw];
      vf[dt][1] = *(const bf16x8*)&vbuf[(dt * 16 + l15) * 64 + (sw ^ 32)];
    }

#pragma unroll
    for (int m = 0; m < 4; ++m) {
      bf16x8 pa[2];
#pragma unroll
      for (int half = 0; half < 2; ++half) {
        f32x4 z0 = {}, z1 = {};
        z0 = MFMA_BF16(kf[2 * half + 0][0], qf[m][0], z0);
        z0 = MFMA_BF16(kf[2 * half + 0][1], qf[m][1], z0);
        z1 = MFMA_BF16(kf[2 * half + 1][0], qf[m][0], z1);
        z1 = MFMA_BF16(kf[2 * half + 1][1], qf[m][1], z1);
        f32x4 p0, p1;
#pragma unroll
        for (int r = 0; r < 4; ++r) {
          p0[r] = __builtin_amdgcn_exp2f(z0[r]);
          p1[r] = __builtin_amdgcn_exp2f(z1[r]);
        }
        l_sum[m] += p0[0] + p0[1] + p0[2] + p0[3] + p1[0] + p1[1] + p1[2] + p1[3];
        union { unsigned u[4]; bf16x8 v; } cv;
        cv.u[0] = pack_bf16x2_trunc(p0[0], p0[1]);
        cv.u[1] = pack_bf16x2_trunc(p0[2], p0[3]);
        cv.u[2] = pack_bf16x2_trunc(p1[0], p1[1]);
        cv.u[3] = pack_bf16x2_trunc(p1[2], p1[3]);
        pa[half] = cv.v;
      }
      __builtin_amdgcn_s_setprio(1);
#pragma unroll
      for (int dt = 0; dt < 4; ++dt) {
        o_acc[dt][m] = MFMA_BF16(vf[dt][0], pa[0], o_acc[dt][m]);
        o_acc[dt][m] = MFMA_BF16(vf[dt][1], pa[1], o_acc[dt][m]);
      }
      __builtin_amdgcn_s_setprio(0);
    }

    // ds_reads of this tile complete before DMA overwrites the buffer
    asm volatile("s_waitcnt lgkmcnt(0)" ::: "memory");
    __builtin_amdgcn_sched_barrier(0);
  }

  // ---- cross-wave reduction ----
  __syncthreads();  // all waves done with their private K/V buffers
  // sums: reduce over quads in-wave, one writer per (mset, l15) -> dead Q region
#pragma unroll
  for (int m = 0; m < 4; ++m) {
    float tm = l_sum[m];
    tm += __shfl_xor(tm, 16);
    tm += __shfl_xor(tm, 32);
    if (quad == 0) ((float*)lQ)[(w * 4 + m) * 16 + l15] = tm;
  }
  // O partials -> dead K/V region: slot (w, dt, m) = 64 lanes x f32x4
  float* part = (float*)(smem + 4096);
#pragma unroll
  for (int dt = 0; dt < 4; ++dt)
#pragma unroll
    for (int m = 0; m < 4; ++m)
      *(f32x4*)&part[((w * 16 + dt * 4 + m) * 64 + lane) * 4] = o_acc[dt][m];
  __syncthreads();
  // wave w combines mset = w and stores q-rows 16w..16w+15
  {
    const int m = w;
    const float* sums = (const float*)lQ;
    const float tsum = sums[(0 * 4 + m) * 16 + l15] + sums[(1 * 4 + m) * 16 + l15] +
                       sums[(2 * 4 + m) * 16 + l15] + sums[(3 * 4 + m) * 16 + l15];
    const float inv = 1.0f / tsum;
    const int mr = qrow0 + m * 16 + l15;
#pragma unroll
    for (int dt = 0; dt < 4; ++dt) {
      f32x4 o = *(const f32x4*)&part[((0 * 16 + dt * 4 + m) * 64 + lane) * 4];
      o += *(const f32x4*)&part[((1 * 16 + dt * 4 + m) * 64 + lane) * 4];
      o += *(const f32x4*)&part[((2 * 16 + dt * 4 + m) * 64 + lane) * 4];
      o += *(const f32x4*)&part[((3 * 16 + dt * 4 + m) * 64 + lane) * 4];
      uint2 ok;
      ok.x = pack_bf16x2(o[0] * inv, o[1] * inv);
      ok.y = pack_bf16x2(o[2] * inv, o[3] * inv);
      *(uint2*)&O[(size_t)mr * 1024 + h * 64 + dt * 16 + quad * 4] = ok;
    }
  }
}

extern "C" void kernel_launch(void* const* d_in, const int* in_sizes, int n_in,
                              void* d_out, int out_size, void* d_ws, size_t ws_size,
                              hipStream_t stream)
{
  (void)in_sizes; (void)n_in; (void)out_size; (void)ws_size;
  const float* keys   = (const float*)d_in[0];
  const float* values = (const float*)d_in[1];
  const float* qk_g   = (const float*)d_in[2];
  const float* qk_b   = (const float*)d_in[3];
  const float* val_g  = (const float*)d_in[4];
  const float* val_b  = (const float*)d_in[5];
  const float* key_g  = (const float*)d_in[6];
  const float* key_b  = (const float*)d_in[7];
  const float* qry_g  = (const float*)d_in[8];
  const float* qry_b  = (const float*)d_in[9];
  const float* w_qk   = (const float*)d_in[10];
  const float* w_v    = (const float*)d_in[11];
  const float* w_out  = (const float*)d_in[12];
  const float* b_out  = (const float*)d_in[13];
  float* out = (float*)d_out;

  const float CEXP = 0.03125f * 1.44269504f;  // ID^-0.5 * log2(e), folded into q-LN

  // R14 workspace map (48MB) — lifetime-disjoint under the merged schedule.
  char* ws = (char*)d_ws;
  const size_t MB = 1024 * 1024;
  bf16* keys_ln   = (bf16*)(ws + 0);        // 8MB   P1w, P2r
  bf16* values_ln = (bf16*)(ws + 8 * MB);   // 8MB   P1w, P2r
  bf16* qk        = (bf16*)(ws + 16 * MB);  // 16MB  P2w, P3r
  bf16* vt        = (bf16*)(ws + 32 * MB);  // 8MB   P2w, P4r
  bf16* qln       = (bf16*)(ws + 0);        // 8MB   P3w, P4r (reuses keys_ln)
  bf16* kln       = (bf16*)(ws + 8 * MB);   // 8MB   P3w, P4r (reuses values_ln)
  bf16* attn      = (bf16*)(ws + 16 * MB);  // 8MB   P4w, P5r (reuses qk)
  bf16* wqkT      = (bf16*)(ws + 40 * MB);  // 4MB   P1w, P2r
  bf16* wvT       = (bf16*)(ws + 44 * MB);  // 2MB   P1w, P2r
  bf16* woutT     = (bf16*)(ws + 46 * MB);  // 2MB   P1w, P5r

  // P1: input layernorms (wave-per-row, 2048 blocks) + weight transposes (1024 blocks)
  prep_kernel<<<dim3(3072), 256, 0, stream>>>(
      keys, values, qk_g, qk_b, val_g, val_b, keys_ln, values_ln,
      w_qk, wqkT, w_v, wvT, w_out, woutT);
  // P2: qk = keys_ln @ w_qk (512 blocks, 128x128) + vt transposed (256 blocks, 128x128)
  gemm_dual_kernel<<<dim3(768), 256, 0, stream>>>(
      keys_ln, wqkT, qk, values_ln, wvT, vt);
  // P3: q/k layernorms (wave-per-row, 2048 blocks); qln pre-scaled by CEXP
  ln2_kernel<bf16><<<dim3(2048), 256, 0, stream>>>(
      qk, qk + 1024, 2048, qry_g, qry_b, key_g, key_b, qln, kln, CEXP, 1.0f);
  // P4: flash attention -> attn (1024 blocks, k-split waves, XCD-affine bh grouping)
  flash_kernel<<<dim3(1024), 256, 0, stream>>>(qln, kln, vt, attn);
  // P5: out = attn @ w_out + b_out (fp32 out), 128x64 tile, 512 blocks, 3 blocks/CU
  gemm_bt_kernel<128, 64, 0, float><<<dim3(16, 32), 256, 0, stream>>>(
      attn, woutT, b_out, out, 1024, 1024, 1);
}